// Round 5
// baseline (190.502 us; speedup 1.0000x reference)
//
#include <hip/hip_runtime.h>
#include <math.h>
#include <stdint.h>

// Problem constants
#define B_ 2
#define L_ 2048
#define D_ 1024
#define H_ 16
#define HD_ 64
// Q scale = 1/8 (softmax scale) * log2(e), folding exp->exp2
#define QSCALE_ 0.1803368801f

typedef __attribute__((ext_vector_type(8))) short short8;   // 8 bf16 = 4 VGPRs (MFMA A/B frag)
typedef __attribute__((ext_vector_type(4))) short short4v;
typedef __attribute__((ext_vector_type(4))) float float4v;  // MFMA C/D frag

#if defined(__has_builtin)
#if __has_builtin(__builtin_amdgcn_exp2f)
#define EXP2F(x) __builtin_amdgcn_exp2f(x)
#endif
#endif
#ifndef EXP2F
#define EXP2F(x) exp2f(x)
#endif

// fp32 -> bf16 round-to-nearest-even (bit pattern as short)
__device__ __forceinline__ short f2bf(float f) {
    union { float f; unsigned u; } x; x.f = f;
    unsigned r = x.u + 0x7fffu + ((x.u >> 16) & 1u);
    return (short)(r >> 16);
}

// bf16 (bit pattern) -> fp32
__device__ __forceinline__ float bf2f(short s) {
    union { unsigned u; float f; } x;
    x.u = ((unsigned)(unsigned short)s) << 16;
    return x.f;
}

__device__ __forceinline__ unsigned fbits(float f) {
    union { float f; unsigned u; } x; x.f = f;
    return x.u;
}

// pack trunc-bf16(a) | trunc-bf16(b)<<16 in ONE v_perm_b32
__device__ __forceinline__ unsigned pk_bf_trunc(float a, float b) {
    return __builtin_amdgcn_perm(fbits(b), fbits(a), 0x07060302u);
}

// convert 8 fp32 (two float4) -> short8 bf16 RNE and store to LDS
__device__ __forceinline__ void st_cvt(short* dst, float4 a, float4 b) {
    short8 r;
    r[0] = f2bf(a.x); r[1] = f2bf(a.y); r[2] = f2bf(a.z); r[3] = f2bf(a.w);
    r[4] = f2bf(b.x); r[5] = f2bf(b.y); r[6] = f2bf(b.z); r[7] = f2bf(b.w);
    *(short8*)dst = r;
}

// ---------------------------------------------------------------------------
// QKV GEMM v5 (R14): cvt_all FUSED — reads fp32 x / w_qkv directly, casts to
// bf16 at LDS-stage time. Prefetch regs stay fp32 (dist-2 pipeline intact;
// converts sit at ds_write, not behind the load wait). Otherwise R12:
// 512 threads (8 waves, 2m x 4n), LDS rows padded to 40 shorts, LDS dbuf,
// 1 barrier/iter. 128x128 tile, BK=32. XCD swizzle.
// Q [b,h,l,d] scaled; K [b,h,l,d]; V^T [b,h,d,slot] PI-PERMUTED kpos.
// ---------------------------------------------------------------------------
#define LDA_ 40   // padded LDS row stride (shorts)
__global__ __launch_bounds__(512) void gemm_qkv_f32(const float* __restrict__ A,
                                                    const float* __restrict__ Bm,
                                                    short* __restrict__ Qb,
                                                    short* __restrict__ Kb,
                                                    short* __restrict__ Vb) {
    __shared__ short smem[20480];   // A dbuf [0,10240) 128xLDA_ x2; B dbuf [10240,20480)
    const int tid = threadIdx.x;
    const int w = tid >> 6, l = tid & 63;   // w = 0..7
    const int lm = l & 15, q = l >> 4;
    const int bid = blockIdx.x;           // 0..767
    const int xcd = bid & 7;
    const int grp = bid >> 3;             // 0..95
    const int n_tile = xcd + 8 * (grp % 3);
    const int m_tile = grp / 3;
    const int m0 = m_tile * 128, n0 = n_tile * 128;
    const int wm = w >> 2, wn = w & 3;    // 2 x 4 wave grid

    // staging: 512 threads cover 128 rows x 4 k-slots; 8 fp32 each per tensor
    const int srow = tid >> 2;            // 0..127
    const int sc8  = (tid & 3) * 8;       // 0,8,16,24 (elements)
    const int soff = srow * LDA_ + sc8;
    const float* Ag = A  + (size_t)(m0 + srow) * 1024 + sc8;
    const float* Bg = Bm + (size_t)(n0 + srow) * 1024 + sc8;

    float4v acc[4][2];
#pragma unroll
    for (int mt = 0; mt < 4; ++mt)
#pragma unroll
        for (int nt = 0; nt < 2; ++nt) acc[mt][nt] = (float4v){0.f, 0.f, 0.f, 0.f};

    {   // stage tile 0 directly
        float4 a00 = *(const float4*)(Ag);
        float4 a01 = *(const float4*)(Ag + 4);
        float4 b00 = *(const float4*)(Bg);
        float4 b01 = *(const float4*)(Bg + 4);
        st_cvt(smem + soff, a00, a01);
        st_cvt(smem + 10240 + soff, b00, b01);
    }
    // tile 1 -> fp32 regs
    float4 ar0 = *(const float4*)(Ag + 32);
    float4 ar1 = *(const float4*)(Ag + 36);
    float4 br0 = *(const float4*)(Bg + 32);
    float4 br1 = *(const float4*)(Bg + 36);

    for (int t = 0; t < 32; ++t) {
        const int cur = t & 1;
        short* Asc = smem + cur * 5120;
        short* Asn = smem + (1 - cur) * 5120;
        short* Bsc = smem + 10240 + cur * 5120;
        short* Bsn = smem + 10240 + (1 - cur) * 5120;

        __syncthreads();

        if (t < 31) {
            st_cvt(Asn + soff, ar0, ar1);
            st_cvt(Bsn + soff, br0, br1);
        }
        if (t < 30) {
            const int k0 = (t + 2) * 32;
            ar0 = *(const float4*)(Ag + k0);
            ar1 = *(const float4*)(Ag + k0 + 4);
            br0 = *(const float4*)(Bg + k0);
            br1 = *(const float4*)(Bg + k0 + 4);
        }

        short8 af[4], bfr[2];
#pragma unroll
        for (int mt = 0; mt < 4; ++mt)
            af[mt] = *(const short8*)(Asc + (wm * 64 + mt * 16 + lm) * LDA_ + q * 8);
#pragma unroll
        for (int nt = 0; nt < 2; ++nt)
            bfr[nt] = *(const short8*)(Bsc + (wn * 32 + nt * 16 + lm) * LDA_ + q * 8);
#pragma unroll
        for (int mt = 0; mt < 4; ++mt)
#pragma unroll
            for (int nt = 0; nt < 2; ++nt)
                acc[mt][nt] = __builtin_amdgcn_mfma_f32_16x16x32_bf16(af[mt], bfr[nt], acc[mt][nt], 0, 0, 0);
    }

    // C layout: col = lane&15, row = quad*4 + reg
    const int which = n0 >> 10;   // uniform per block: 0=Q, 1=K, 2=V
    if (which < 2) {
        short* dst = (which == 0) ? Qb : Kb;
        const float sc = (which == 0) ? QSCALE_ : 1.0f;
#pragma unroll
        for (int half = 0; half < 2; ++half) {
            __syncthreads();
            if (wm == half) {
#pragma unroll
                for (int mt = 0; mt < 4; ++mt)
#pragma unroll
                    for (int nt = 0; nt < 2; ++nt)
#pragma unroll
                        for (int r = 0; r < 4; ++r)
                            smem[(mt * 16 + q * 4 + r) * 128 + wn * 32 + nt * 16 + lm] =
                                f2bf(acc[mt][nt][r] * sc);
            }
            __syncthreads();
#pragma unroll
            for (int j = 0; j < 2; ++j) {
                const int x = tid + 512 * j;        // 0..1023 = 64 rows x 16 col-groups
                const int row = x >> 4, c = x & 15;
                short8 v = *(const short8*)(smem + row * 128 + c * 8);
                const int m = m0 + half * 64 + row;
                const int b = m >> 11, ll = m & 2047;
                const int n = n0 + c * 8;
                const int hh = (n & 1023) >> 6, d = n & 63;
                *(short8*)(dst + (((size_t)b * H_ + hh) * L_ + ll) * HD_ + d) = v;
            }
        }
    } else {
        // V^T pi-permuted: slot within 64-tile = (mt>>1)*32 + q*8 + (mt&1)*4 + r.
        const int mbase = m0 + wm * 64;              // 64-aligned token base
        const int b = mbase >> 11;
        const int llb = (mbase & 2047);
#pragma unroll
        for (int mt = 0; mt < 4; ++mt) {
            const int ll = llb + (mt >> 1) * 32 + q * 8 + (mt & 1) * 4;
#pragma unroll
            for (int nt = 0; nt < 2; ++nt) {
                const int n = n0 + wn * 32 + nt * 16 + lm;
                const int h = (n & 1023) >> 6, d = n & 63;
                short4v pk;
                pk.x = f2bf(acc[mt][nt][0]); pk.y = f2bf(acc[mt][nt][1]);
                pk.z = f2bf(acc[mt][nt][2]); pk.w = f2bf(acc[mt][nt][3]);
                *(short4v*)(Vb + (((size_t)b * H_ + h) * HD_ + d) * L_ + ll) = pk;
            }
        }
    }
}

// ---------------------------------------------------------------------------
// Flash attention v8 (R13, unchanged): split-KV x2 + nq=2 (32 q-rows/wave).
// grid 512 = 32bh x 8qt(256 rows) x 2 kv-halves, 512 threads, 2 blocks/CU.
// Partial O (unnormalized bf16) + partial row sums written; proj merges.
// Pi-permuted V: P never touches LDS. K/V dbuf, dist-2 reg prefetch,
// 1 barrier/iter. XCD swizzle.
// ---------------------------------------------------------------------------
__global__ __launch_bounds__(512) void attn_mfma(const short* __restrict__ Qb,
                                                 const short* __restrict__ Kb,
                                                 const short* __restrict__ Vtg,
                                                 short* __restrict__ Op0,
                                                 short* __restrict__ Op1,
                                                 float* __restrict__ Lp0,
                                                 float* __restrict__ Lp1) {
    __shared__ short KV[4 * 4096];   // buf0: K,V (0..8191); buf1: K,V (8192..16383)

    const int tid = threadIdx.x;
    const int w = tid >> 6, l = tid & 63;   // w = 0..7
    const int lm = l & 15, q = l >> 4;
    const int bid = blockIdx.x;             // 0..511
    const int xcd = bid & 7;
    const int grp = bid >> 3;               // 0..63
    const int combo = xcd * 8 + (grp >> 3); // 0..63: (bh, half), XCD-local
    const int bh = combo >> 1;              // 0..31
    const int half = combo & 1;             // kv half
    const int qt = grp & 7;                 // 0..7 (256-row q-tiles)

    const short* Qg = Qb  + ((size_t)bh * L_ + qt * 256) * HD_;
    const short* Kg = Kb  + ((size_t)bh * L_ + half * 1024) * HD_;
    const short* Vg = Vtg + (size_t)bh * HD_ * L_ + half * 1024;

    // Q fragments: direct global loads (one-time; rows are wave-private)
    short8 qf[2][2];
#pragma unroll
    for (int nq = 0; nq < 2; ++nq)
#pragma unroll
        for (int kh = 0; kh < 2; ++kh)
            qf[nq][kh] = *(const short8*)(Qg + (size_t)(w * 32 + nq * 16 + lm) * HD_ + (kh * 4 + q) * 8);

    // K/V staging geometry: 512 threads, 1 short8 each per tile per tensor
    const int srow = tid >> 3;            // 0..63
    const int sc   = tid & 7;             // 0..7
    const int koff = srow * 64 + ((sc ^ (srow & 7)) * 8);

    // tile 0 -> buf0 now; tile 1 -> regs
    {
        short8 ka = *(const short8*)(Kg + (size_t)srow * 64 + sc * 8);
        short8 va = *(const short8*)(Vg + (size_t)srow * L_ + sc * 8);
        *(short8*)(KV + koff) = ka;
        *(short8*)(KV + 4096 + koff) = va;
    }
    short8 kra = *(const short8*)(Kg + (size_t)(64 + srow) * 64 + sc * 8);
    short8 vra = *(const short8*)(Vg + (size_t)srow * L_ + 64 + sc * 8);

    __syncthreads();   // tile0 staged

    // hoisted frag offsets (iter-invariant)
    int offA0[4], offA1[4], offV[2][4];
#pragma unroll
    for (int nt = 0; nt < 4; ++nt) {
        const int arow = nt * 16 + lm;
        offA0[nt] = arow * 64 + ((q ^ (arow & 7)) * 8);
        offA1[nt] = arow * 64 + (((4 + q) ^ (arow & 7)) * 8);
#pragma unroll
        for (int kh = 0; kh < 2; ++kh)
            offV[kh][nt] = arow * 64 + (((kh * 4 + q) ^ (arow & 7)) * 8);
    }

    float4v o[4][2];
#pragma unroll
    for (int mt = 0; mt < 4; ++mt)
#pragma unroll
        for (int nq = 0; nq < 2; ++nq) o[mt][nq] = (float4v){0.f, 0.f, 0.f, 0.f};
    float lsum[2] = {0.f, 0.f};

#pragma unroll 2
    for (int t = 0; t < 16; ++t) {
        const int cur = t & 1;
        short* Kl = KV + cur * 8192;
        short* Vt = Kl + 4096;
        short* Kn = KV + (1 - cur) * 8192;
        short* Vn = Kn + 4096;

        __syncthreads();   // prev iter's reads of buf[!cur] done; buf[cur] writes visible

        if (t < 15) {      // stage tile t+1 into the other buffer
            *(short8*)(Kn + koff) = kra;
            *(short8*)(Vn + koff) = vra;
        }
        if (t < 14) {      // prefetch tile t+2
            kra = *(const short8*)(Kg + (size_t)((t + 2) * 64 + srow) * 64 + sc * 8);
            vra = *(const short8*)(Vg + (size_t)srow * L_ + (t + 2) * 64 + sc * 8);
        }

        // S^T = K Q^T : A = K rows (kpos), B = Q rows (qrow)
        float4v st[4][2];
#pragma unroll
        for (int nt = 0; nt < 4; ++nt) {
            short8 a0 = *(const short8*)(Kl + offA0[nt]);
            short8 a1 = *(const short8*)(Kl + offA1[nt]);
#pragma unroll
            for (int nq = 0; nq < 2; ++nq) {
                float4v z = (float4v){0.f, 0.f, 0.f, 0.f};
                z = __builtin_amdgcn_mfma_f32_16x16x32_bf16(a0, qf[nq][0], z, 0, 0, 0);
                z = __builtin_amdgcn_mfma_f32_16x16x32_bf16(a1, qf[nq][1], z, 0, 0, 0);
                st[nt][nq] = z;
            }
        }

        // exp2 + build P B-frags IN REGISTERS (pi-permutation: value (nt,r)
        // -> B slot kh=nt>>1, j=(nt&1)*4+r).
        short8 pb[2][2];
#pragma unroll
        for (int nq = 0; nq < 2; ++nq) {
            float e[4][4];
#pragma unroll
            for (int nt = 0; nt < 4; ++nt) {
                e[nt][0] = EXP2F(st[nt][nq][0]);
                e[nt][1] = EXP2F(st[nt][nq][1]);
                e[nt][2] = EXP2F(st[nt][nq][2]);
                e[nt][3] = EXP2F(st[nt][nq][3]);
                lsum[nq] += (e[nt][0] + e[nt][1]) + (e[nt][2] + e[nt][3]);
            }
            union { short8 s8; unsigned u[4]; } p0, p1;
            p0.u[0] = pk_bf_trunc(e[0][0], e[0][1]);
            p0.u[1] = pk_bf_trunc(e[0][2], e[0][3]);
            p0.u[2] = pk_bf_trunc(e[1][0], e[1][1]);
            p0.u[3] = pk_bf_trunc(e[1][2], e[1][3]);
            p1.u[0] = pk_bf_trunc(e[2][0], e[2][1]);
            p1.u[1] = pk_bf_trunc(e[2][2], e[2][3]);
            p1.u[2] = pk_bf_trunc(e[3][0], e[3][1]);
            p1.u[3] = pk_bf_trunc(e[3][2], e[3][3]);
            pb[0][nq] = p0.s8;
            pb[1][nq] = p1.s8;
        }

        // O^T += V^T P^T : A = Vt rows (d) [pi-permuted slots], B = pb regs
#pragma unroll
        for (int kh = 0; kh < 2; ++kh)
#pragma unroll
            for (int mt = 0; mt < 4; ++mt) {
                short8 va = *(const short8*)(Vt + offV[kh][mt]);
#pragma unroll
                for (int nq = 0; nq < 2; ++nq)
                    o[mt][nq] = __builtin_amdgcn_mfma_f32_16x16x32_bf16(va, pb[kh][nq], o[mt][nq], 0, 0, 0);
            }
    }

    // reduce row-sums across the 4 quads (same lm); store UNNORMALIZED partials
#pragma unroll
    for (int nq = 0; nq < 2; ++nq) {
        float s = lsum[nq];
        s += __shfl_xor(s, 16);
        s += __shfl_xor(s, 32);
        lsum[nq] = s;
    }
    short* Op = half ? Op1 : Op0;
    float* Lp = half ? Lp1 : Lp0;
    short* OgBase = Op + ((size_t)bh * L_ + qt * 256) * HD_;
#pragma unroll
    for (int nq = 0; nq < 2; ++nq) {
        const int qrow = w * 32 + nq * 16 + lm;
#pragma unroll
        for (int mt = 0; mt < 4; ++mt) {
            short4v pk;
            pk.x = f2bf(o[mt][nq][0]);
            pk.y = f2bf(o[mt][nq][1]);
            pk.z = f2bf(o[mt][nq][2]);
            pk.w = f2bf(o[mt][nq][3]);
            *(short4v*)(OgBase + (size_t)qrow * 64 + mt * 16 + q * 4) = pk;
        }
    }
    if (l < 16) {
        const size_t rbase = (size_t)bh * L_ + qt * 256 + w * 32 + l;
        Lp[rbase]      = lsum[0];
        Lp[rbase + 16] = lsum[1];
    }
}

// ---------------------------------------------------------------------------
// Proj GEMM v4 (R14): combine_o FUSED into A-staging -- reads both split-KV
// partials + row-sums, normalizes while staging (identical numerics to the
// old combine-then-stage). Also reads fp32 w_proj directly (cvt_all gone).
// out = O Wp^T, fp32 out. 64x128, BK=32, reg-prefetch dist 2 + LDS dbuf +
// 1 barrier/iter, padded LDS rows. XCD swizzle (W L2-resident).
// ---------------------------------------------------------------------------
__global__ __launch_bounds__(256) void gemm_proj_fused(const short* __restrict__ Op0,
                                                       const short* __restrict__ Op1,
                                                       const float* __restrict__ Lp0,
                                                       const float* __restrict__ Lp1,
                                                       const float* __restrict__ Wp,
                                                       float* __restrict__ out) {
    __shared__ short As[2 * 2560];   // 64 x LDA_ per buf
    __shared__ short Bs[2 * 5120];   // 128 x LDA_ per buf
    const int tid = threadIdx.x;
    const int w = tid >> 6, l = tid & 63;
    const int lm = l & 15, q = l >> 4;
    const int bid = blockIdx.x;           // 0..511
    const int m0 = (bid >> 3) * 64, n0 = (bid & 7) * 128;
    const int wm = w & 1, wn = w >> 1;
    const int b = m0 >> 11, l0 = m0 & 2047;

    const int srow = tid >> 2;            // 0..63
    const int sc8  = (tid & 3) * 8;       // 0,8,16,24 (elements)
    const int aoff = srow * LDA_ + sc8;
    const int boff0 = aoff;
    const int boff1 = aoff + 64 * LDA_;
    const int arow_g = l0 + srow;         // token row this thread stages (fixed)
    const float* Bg = Wp + (size_t)(n0 + srow) * 1024 + sc8;

    float4v acc[2][4];
#pragma unroll
    for (int mt = 0; mt < 2; ++mt)
#pragma unroll
        for (int nt = 0; nt < 4; ++nt) acc[mt][nt] = (float4v){0.f, 0.f, 0.f, 0.f};

    {   // stage tile 0 directly: hh=0, d=sc8
        const size_t li = (size_t)(b * H_) * L_ + arow_g;
        const size_t ai = li * HD_ + sc8;
        short8 x0 = *(const short8*)(Op0 + ai);
        short8 x1 = *(const short8*)(Op1 + ai);
        const float inv = 1.f / (Lp0[li] + Lp1[li]);
        short8 r;
#pragma unroll
        for (int j = 0; j < 8; ++j)
            r[j] = f2bf((bf2f(x0[j]) + bf2f(x1[j])) * inv);
        *(short8*)(As + aoff) = r;
        float4 c0 = *(const float4*)(Bg);
        float4 c1 = *(const float4*)(Bg + 4);
        float4 c2 = *(const float4*)(Bg + 64 * 1024);
        float4 c3 = *(const float4*)(Bg + 64 * 1024 + 4);
        st_cvt(Bs + boff0, c0, c1);
        st_cvt(Bs + boff1, c2, c3);
    }
    // tile 1 -> regs: hh=0, d=32+sc8
    short8 ap0, ap1;
    float lsA;
    {
        const size_t li = (size_t)(b * H_) * L_ + arow_g;
        const size_t ai = li * HD_ + 32 + sc8;
        ap0 = *(const short8*)(Op0 + ai);
        ap1 = *(const short8*)(Op1 + ai);
        lsA = Lp0[li] + Lp1[li];
    }
    float4 bw00 = *(const float4*)(Bg + 32);
    float4 bw01 = *(const float4*)(Bg + 36);
    float4 bw10 = *(const float4*)(Bg + 64 * 1024 + 32);
    float4 bw11 = *(const float4*)(Bg + 64 * 1024 + 36);

    for (int t = 0; t < 32; ++t) {
        const int cur = t & 1;
        short* Asc = As + cur * 2560;
        short* Asn = As + (1 - cur) * 2560;
        short* Bsc = Bs + cur * 5120;
        short* Bsn = Bs + (1 - cur) * 5120;

        __syncthreads();

        if (t < 31) {
            const float inv = 1.f / lsA;
            short8 r;
#pragma unroll
            for (int j = 0; j < 8; ++j)
                r[j] = f2bf((bf2f(ap0[j]) + bf2f(ap1[j])) * inv);
            *(short8*)(Asn + aoff) = r;
            st_cvt(Bsn + boff0, bw00, bw01);
            st_cvt(Bsn + boff1, bw10, bw11);
        }
        if (t < 30) {
            const int tn = t + 2;
            const int hh = tn >> 1, d = (tn & 1) * 32 + sc8;
            const size_t li = (size_t)(b * H_ + hh) * L_ + arow_g;
            const size_t ai = li * HD_ + d;
            ap0 = *(const short8*)(Op0 + ai);
            ap1 = *(const short8*)(Op1 + ai);
            lsA = Lp0[li] + Lp1[li];
            bw00 = *(const float4*)(Bg + tn * 32);
            bw01 = *(const float4*)(Bg + tn * 32 + 4);
            bw10 = *(const float4*)(Bg + 64 * 1024 + tn * 32);
            bw11 = *(const float4*)(Bg + 64 * 1024 + tn * 32 + 4);
        }

        short8 af[2], bfr[4];
#pragma unroll
        for (int mt = 0; mt < 2; ++mt)
            af[mt] = *(const short8*)(Asc + (wm * 32 + mt * 16 + lm) * LDA_ + q * 8);
#pragma unroll
        for (int nt = 0; nt < 4; ++nt)
            bfr[nt] = *(const short8*)(Bsc + (wn * 64 + nt * 16 + lm) * LDA_ + q * 8);
#pragma unroll
        for (int mt = 0; mt < 2; ++mt)
#pragma unroll
            for (int nt = 0; nt < 4; ++nt)
                acc[mt][nt] = __builtin_amdgcn_mfma_f32_16x16x32_bf16(af[mt], bfr[nt], acc[mt][nt], 0, 0, 0);
    }

#pragma unroll
    for (int mt = 0; mt < 2; ++mt)
#pragma unroll
        for (int nt = 0; nt < 4; ++nt)
#pragma unroll
            for (int r = 0; r < 4; ++r) {
                const int m = m0 + wm * 32 + mt * 16 + q * 4 + r;
                const int n = n0 + wn * 64 + nt * 16 + lm;
                out[(size_t)m * 1024 + n] = acc[mt][nt][r];
            }
}

// ---------------------------------------------------------------------------
extern "C" void kernel_launch(void* const* d_in, const int* in_sizes, int n_in,
                              void* d_out, int out_size, void* d_ws, size_t ws_size,
                              hipStream_t stream) {
    (void)in_sizes; (void)n_in; (void)out_size; (void)ws_size;
    const float* x      = (const float*)d_in[0];
    const float* w_qkv  = (const float*)d_in[1];
    const float* w_proj = (const float*)d_in[2];

    char* ws = (char*)d_ws;                       // 48 MiB used
    short* Op0    = (short*)(ws);                 // 8 MiB  partial O, kv-half 0
    float* Lp0    = (float*)(ws + (8u  << 20));   // 256 KB row-sums half 0
    float* Lp1    = (float*)(ws + (8u  << 20) + (256u << 10)); // 256 KB half 1
    short* Qb     = (short*)(ws + (16u << 20));   // 8 MiB  [b,h,l,d], scaled
    short* Kb     = (short*)(ws + (24u << 20));   // 8 MiB  [b,h,l,d]
    short* Vb     = (short*)(ws + (32u << 20));   // 8 MiB  [b,h,d,slot] pi-permuted V^T
    short* Op1    = (short*)(ws + (40u << 20));   // 8 MiB  partial O, kv-half 1

    gemm_qkv_f32   <<<768, 512, 0, stream>>>(x, w_qkv, Qb, Kb, Vb);
    attn_mfma      <<<512, 512, 0, stream>>>(Qb, Kb, Vb, Op0, Op1, Lp0, Lp1);
    gemm_proj_fused<<<512, 256, 0, stream>>>(Op0, Op1, Lp0, Lp1, w_proj, (float*)d_out);
}

// Round 6
// 178.439 us; speedup vs baseline: 1.0676x; 1.0676x over previous
//
#include <hip/hip_runtime.h>
#include <math.h>
#include <stdint.h>

// Problem constants
#define B_ 2
#define L_ 2048
#define D_ 1024
#define H_ 16
#define HD_ 64
// Q scale = 1/8 (softmax scale) * log2(e), folding exp->exp2
#define QSCALE_ 0.1803368801f

typedef __attribute__((ext_vector_type(8))) short short8;   // 8 bf16 = 4 VGPRs (MFMA A/B frag)
typedef __attribute__((ext_vector_type(4))) short short4v;
typedef __attribute__((ext_vector_type(4))) float float4v;  // MFMA C/D frag

#if defined(__has_builtin)
#if __has_builtin(__builtin_amdgcn_exp2f)
#define EXP2F(x) __builtin_amdgcn_exp2f(x)
#endif
#endif
#ifndef EXP2F
#define EXP2F(x) exp2f(x)
#endif

// fp32 -> bf16 round-to-nearest-even (bit pattern as short)
__device__ __forceinline__ short f2bf(float f) {
    union { float f; unsigned u; } x; x.f = f;
    unsigned r = x.u + 0x7fffu + ((x.u >> 16) & 1u);
    return (short)(r >> 16);
}

// bf16 (bit pattern) -> fp32
__device__ __forceinline__ float bf2f(short s) {
    union { unsigned u; float f; } x;
    x.u = ((unsigned)(unsigned short)s) << 16;
    return x.f;
}

__device__ __forceinline__ unsigned fbits(float f) {
    union { float f; unsigned u; } x; x.f = f;
    return x.u;
}

// pack trunc-bf16(a) | trunc-bf16(b)<<16 in ONE v_perm_b32
__device__ __forceinline__ unsigned pk_bf_trunc(float a, float b) {
    return __builtin_amdgcn_perm(fbits(b), fbits(a), 0x07060302u);
}

// ---------------------------------------------------------------------------
// Cast ALL inputs fp32->bf16 in one launch. (Restored from R5's failed fusion:
// fusing the cast into qkv doubled FETCH, tripled staging VALU -> +12 us.)
// ---------------------------------------------------------------------------
__global__ __launch_bounds__(256) void cvt_all(const float* __restrict__ x,
                                               const float* __restrict__ wqkv,
                                               const float* __restrict__ wproj,
                                               short* __restrict__ xb,
                                               short* __restrict__ wqkvb,
                                               short* __restrict__ wprojb) {
    int i = blockIdx.x * 256 + threadIdx.x;   // grid 8192*256 = 2097152 exactly
    const float* in;
    short* out;
    int idx;
    if (i < 1048576)      { in = x;     out = xb;     idx = i; }
    else if (i < 1835008) { in = wqkv;  out = wqkvb;  idx = i - 1048576; }
    else                  { in = wproj; out = wprojb; idx = i - 1835008; }
    float4 v = ((const float4*)in)[idx];
    short4v o;
    o.x = f2bf(v.x); o.y = f2bf(v.y); o.z = f2bf(v.z); o.w = f2bf(v.w);
    ((short4v*)out)[idx] = o;
}

// ---------------------------------------------------------------------------
// QKV GEMM v6 (R15): BK 32 -> 64. Halves barrier count (32 -> 16 iters),
// doubles MFMA work per phase (16/wave between barriers), prefetch dist 2
// in 64-wide K units. LDS 74 KB/block (2 blocks/CU). Rows padded to 72
// shorts (same bank distribution class as the proven 40-pad).
// 512 threads (8 waves, 2m x 4n, 64x32 acc/wave). 128x128 tile. XCD swizzle.
// Q [b,h,l,d] scaled; K [b,h,l,d]; V^T [b,h,d,slot] PI-PERMUTED kpos:
// slot = (mt>>1)*32 + q*8 + (mt&1)*4 + r, so attention's P stays in regs.
// ---------------------------------------------------------------------------
#define LDK_ 72   // qkv padded LDS row stride (shorts), BK=64
__global__ __launch_bounds__(512) void gemm_qkv_bf16(const short* __restrict__ A,
                                                     const short* __restrict__ Bm,
                                                     short* __restrict__ Qb,
                                                     short* __restrict__ Kb,
                                                     short* __restrict__ Vb) {
    __shared__ short smem[36864];   // As dbuf [0,18432) 2x(128xLDK_); Bs dbuf [18432,36864)
    const int tid = threadIdx.x;
    const int w = tid >> 6, l = tid & 63;   // w = 0..7
    const int lm = l & 15, q = l >> 4;
    const int bid = blockIdx.x;           // 0..767
    const int xcd = bid & 7;
    const int grp = bid >> 3;             // 0..95
    const int n_tile = xcd + 8 * (grp % 3);
    const int m_tile = grp / 3;
    const int m0 = m_tile * 128, n0 = n_tile * 128;
    const int wm = w >> 2, wn = w & 3;    // 2 x 4 wave grid

    // staging: 512 threads cover 128 rows x (2x8)-short slots of the 64-wide K
    const int srow = tid >> 2;            // 0..127
    const int sc8  = (tid & 3) * 8;       // 0,8,16,24
    const int soff = srow * LDK_ + sc8;
    const short* Ag = A  + (size_t)(m0 + srow) * 1024 + sc8;
    const short* Bg = Bm + (size_t)(n0 + srow) * 1024 + sc8;

    float4v acc[4][2];
#pragma unroll
    for (int mt = 0; mt < 4; ++mt)
#pragma unroll
        for (int nt = 0; nt < 2; ++nt) acc[mt][nt] = (float4v){0.f, 0.f, 0.f, 0.f};

    {   // stage tile 0 (k 0..63)
        *(short8*)(smem + soff)              = *(const short8*)(Ag);
        *(short8*)(smem + soff + 32)         = *(const short8*)(Ag + 32);
        *(short8*)(smem + 18432 + soff)      = *(const short8*)(Bg);
        *(short8*)(smem + 18432 + soff + 32) = *(const short8*)(Bg + 32);
    }
    // tile 1 -> regs
    short8 ar0 = *(const short8*)(Ag + 64);
    short8 ar1 = *(const short8*)(Ag + 96);
    short8 br0 = *(const short8*)(Bg + 64);
    short8 br1 = *(const short8*)(Bg + 96);

    for (int t = 0; t < 16; ++t) {
        const int cur = t & 1;
        short* Asc = smem + cur * 9216;
        short* Asn = smem + (1 - cur) * 9216;
        short* Bsc = smem + 18432 + cur * 9216;
        short* Bsn = smem + 18432 + (1 - cur) * 9216;

        __syncthreads();

        if (t < 15) {
            *(short8*)(Asn + soff)      = ar0;
            *(short8*)(Asn + soff + 32) = ar1;
            *(short8*)(Bsn + soff)      = br0;
            *(short8*)(Bsn + soff + 32) = br1;
        }
        if (t < 14) {
            const int k0 = (t + 2) * 64;
            ar0 = *(const short8*)(Ag + k0);
            ar1 = *(const short8*)(Ag + k0 + 32);
            br0 = *(const short8*)(Bg + k0);
            br1 = *(const short8*)(Bg + k0 + 32);
        }

        short8 af[4][2], bfr[2][2];
#pragma unroll
        for (int mt = 0; mt < 4; ++mt)
#pragma unroll
            for (int kk = 0; kk < 2; ++kk)
                af[mt][kk] = *(const short8*)(Asc + (wm * 64 + mt * 16 + lm) * LDK_ + kk * 32 + q * 8);
#pragma unroll
        for (int nt = 0; nt < 2; ++nt)
#pragma unroll
            for (int kk = 0; kk < 2; ++kk)
                bfr[nt][kk] = *(const short8*)(Bsc + (wn * 32 + nt * 16 + lm) * LDK_ + kk * 32 + q * 8);
#pragma unroll
        for (int kk = 0; kk < 2; ++kk)
#pragma unroll
            for (int mt = 0; mt < 4; ++mt)
#pragma unroll
                for (int nt = 0; nt < 2; ++nt)
                    acc[mt][nt] = __builtin_amdgcn_mfma_f32_16x16x32_bf16(af[mt][kk], bfr[nt][kk], acc[mt][nt], 0, 0, 0);
    }

    // C layout: col = lane&15, row = quad*4 + reg
    const int which = n0 >> 10;   // uniform per block: 0=Q, 1=K, 2=V
    if (which < 2) {
        short* dst = (which == 0) ? Qb : Kb;
        const float sc = (which == 0) ? QSCALE_ : 1.0f;
#pragma unroll
        for (int half = 0; half < 2; ++half) {
            __syncthreads();
            if (wm == half) {
#pragma unroll
                for (int mt = 0; mt < 4; ++mt)
#pragma unroll
                    for (int nt = 0; nt < 2; ++nt)
#pragma unroll
                        for (int r = 0; r < 4; ++r)
                            smem[(mt * 16 + q * 4 + r) * 128 + wn * 32 + nt * 16 + lm] =
                                f2bf(acc[mt][nt][r] * sc);
            }
            __syncthreads();
#pragma unroll
            for (int j = 0; j < 2; ++j) {
                const int x = tid + 512 * j;        // 0..1023 = 64 rows x 16 col-groups
                const int row = x >> 4, c = x & 15;
                short8 v = *(const short8*)(smem + row * 128 + c * 8);
                const int m = m0 + half * 64 + row;
                const int b = m >> 11, ll = m & 2047;
                const int n = n0 + c * 8;
                const int hh = (n & 1023) >> 6, d = n & 63;
                *(short8*)(dst + (((size_t)b * H_ + hh) * L_ + ll) * HD_ + d) = v;
            }
        }
    } else {
        // V^T pi-permuted: slot within 64-tile = (mt>>1)*32 + q*8 + (mt&1)*4 + r.
        const int mbase = m0 + wm * 64;              // 64-aligned token base
        const int b = mbase >> 11;
        const int llb = (mbase & 2047);
#pragma unroll
        for (int mt = 0; mt < 4; ++mt) {
            const int ll = llb + (mt >> 1) * 32 + q * 8 + (mt & 1) * 4;
#pragma unroll
            for (int nt = 0; nt < 2; ++nt) {
                const int n = n0 + wn * 32 + nt * 16 + lm;
                const int h = (n & 1023) >> 6, d = n & 63;
                short4v pk;
                pk.x = f2bf(acc[mt][nt][0]); pk.y = f2bf(acc[mt][nt][1]);
                pk.z = f2bf(acc[mt][nt][2]); pk.w = f2bf(acc[mt][nt][3]);
                *(short4v*)(Vb + (((size_t)b * H_ + h) * HD_ + d) * L_ + ll) = pk;
            }
        }
    }
}

// ---------------------------------------------------------------------------
// Flash attention v8 (R13, unchanged): split-KV x2 + nq=2 (32 q-rows/wave).
// grid 512 = 32bh x 8qt(256 rows) x 2 kv-halves, 512 threads, 2 blocks/CU.
// Partial O (unnormalized bf16) + partial row sums written; proj merges.
// Pi-permuted V: P never touches LDS. K/V dbuf, dist-2 reg prefetch,
// 1 barrier/iter. XCD swizzle.
// ---------------------------------------------------------------------------
__global__ __launch_bounds__(512) void attn_mfma(const short* __restrict__ Qb,
                                                 const short* __restrict__ Kb,
                                                 const short* __restrict__ Vtg,
                                                 short* __restrict__ Op0,
                                                 short* __restrict__ Op1,
                                                 float* __restrict__ Lp0,
                                                 float* __restrict__ Lp1) {
    __shared__ short KV[4 * 4096];   // buf0: K,V (0..8191); buf1: K,V (8192..16383)

    const int tid = threadIdx.x;
    const int w = tid >> 6, l = tid & 63;   // w = 0..7
    const int lm = l & 15, q = l >> 4;
    const int bid = blockIdx.x;             // 0..511
    const int xcd = bid & 7;
    const int grp = bid >> 3;               // 0..63
    const int combo = xcd * 8 + (grp >> 3); // 0..63: (bh, half), XCD-local
    const int bh = combo >> 1;              // 0..31
    const int half = combo & 1;             // kv half
    const int qt = grp & 7;                 // 0..7 (256-row q-tiles)

    const short* Qg = Qb  + ((size_t)bh * L_ + qt * 256) * HD_;
    const short* Kg = Kb  + ((size_t)bh * L_ + half * 1024) * HD_;
    const short* Vg = Vtg + (size_t)bh * HD_ * L_ + half * 1024;

    // Q fragments: direct global loads (one-time; rows are wave-private)
    short8 qf[2][2];
#pragma unroll
    for (int nq = 0; nq < 2; ++nq)
#pragma unroll
        for (int kh = 0; kh < 2; ++kh)
            qf[nq][kh] = *(const short8*)(Qg + (size_t)(w * 32 + nq * 16 + lm) * HD_ + (kh * 4 + q) * 8);

    // K/V staging geometry: 512 threads, 1 short8 each per tile per tensor
    const int srow = tid >> 3;            // 0..63
    const int sc   = tid & 7;             // 0..7
    const int koff = srow * 64 + ((sc ^ (srow & 7)) * 8);

    // tile 0 -> buf0 now; tile 1 -> regs
    {
        short8 ka = *(const short8*)(Kg + (size_t)srow * 64 + sc * 8);
        short8 va = *(const short8*)(Vg + (size_t)srow * L_ + sc * 8);
        *(short8*)(KV + koff) = ka;
        *(short8*)(KV + 4096 + koff) = va;
    }
    short8 kra = *(const short8*)(Kg + (size_t)(64 + srow) * 64 + sc * 8);
    short8 vra = *(const short8*)(Vg + (size_t)srow * L_ + 64 + sc * 8);

    __syncthreads();   // tile0 staged

    // hoisted frag offsets (iter-invariant)
    int offA0[4], offA1[4], offV[2][4];
#pragma unroll
    for (int nt = 0; nt < 4; ++nt) {
        const int arow = nt * 16 + lm;
        offA0[nt] = arow * 64 + ((q ^ (arow & 7)) * 8);
        offA1[nt] = arow * 64 + (((4 + q) ^ (arow & 7)) * 8);
#pragma unroll
        for (int kh = 0; kh < 2; ++kh)
            offV[kh][nt] = arow * 64 + (((kh * 4 + q) ^ (arow & 7)) * 8);
    }

    float4v o[4][2];
#pragma unroll
    for (int mt = 0; mt < 4; ++mt)
#pragma unroll
        for (int nq = 0; nq < 2; ++nq) o[mt][nq] = (float4v){0.f, 0.f, 0.f, 0.f};
    float lsum[2] = {0.f, 0.f};

#pragma unroll 2
    for (int t = 0; t < 16; ++t) {
        const int cur = t & 1;
        short* Kl = KV + cur * 8192;
        short* Vt = Kl + 4096;
        short* Kn = KV + (1 - cur) * 8192;
        short* Vn = Kn + 4096;

        __syncthreads();   // prev iter's reads of buf[!cur] done; buf[cur] writes visible

        if (t < 15) {      // stage tile t+1 into the other buffer
            *(short8*)(Kn + koff) = kra;
            *(short8*)(Vn + koff) = vra;
        }
        if (t < 14) {      // prefetch tile t+2
            kra = *(const short8*)(Kg + (size_t)((t + 2) * 64 + srow) * 64 + sc * 8);
            vra = *(const short8*)(Vg + (size_t)srow * L_ + (t + 2) * 64 + sc * 8);
        }

        // S^T = K Q^T : A = K rows (kpos), B = Q rows (qrow)
        float4v st[4][2];
#pragma unroll
        for (int nt = 0; nt < 4; ++nt) {
            short8 a0 = *(const short8*)(Kl + offA0[nt]);
            short8 a1 = *(const short8*)(Kl + offA1[nt]);
#pragma unroll
            for (int nq = 0; nq < 2; ++nq) {
                float4v z = (float4v){0.f, 0.f, 0.f, 0.f};
                z = __builtin_amdgcn_mfma_f32_16x16x32_bf16(a0, qf[nq][0], z, 0, 0, 0);
                z = __builtin_amdgcn_mfma_f32_16x16x32_bf16(a1, qf[nq][1], z, 0, 0, 0);
                st[nt][nq] = z;
            }
        }

        // exp2 + build P B-frags IN REGISTERS (pi-permutation: value (nt,r)
        // -> B slot kh=nt>>1, j=(nt&1)*4+r).
        short8 pb[2][2];
#pragma unroll
        for (int nq = 0; nq < 2; ++nq) {
            float e[4][4];
#pragma unroll
            for (int nt = 0; nt < 4; ++nt) {
                e[nt][0] = EXP2F(st[nt][nq][0]);
                e[nt][1] = EXP2F(st[nt][nq][1]);
                e[nt][2] = EXP2F(st[nt][nq][2]);
                e[nt][3] = EXP2F(st[nt][nq][3]);
                lsum[nq] += (e[nt][0] + e[nt][1]) + (e[nt][2] + e[nt][3]);
            }
            union { short8 s8; unsigned u[4]; } p0, p1;
            p0.u[0] = pk_bf_trunc(e[0][0], e[0][1]);
            p0.u[1] = pk_bf_trunc(e[0][2], e[0][3]);
            p0.u[2] = pk_bf_trunc(e[1][0], e[1][1]);
            p0.u[3] = pk_bf_trunc(e[1][2], e[1][3]);
            p1.u[0] = pk_bf_trunc(e[2][0], e[2][1]);
            p1.u[1] = pk_bf_trunc(e[2][2], e[2][3]);
            p1.u[2] = pk_bf_trunc(e[3][0], e[3][1]);
            p1.u[3] = pk_bf_trunc(e[3][2], e[3][3]);
            pb[0][nq] = p0.s8;
            pb[1][nq] = p1.s8;
        }

        // O^T += V^T P^T : A = Vt rows (d) [pi-permuted slots], B = pb regs
#pragma unroll
        for (int kh = 0; kh < 2; ++kh)
#pragma unroll
            for (int mt = 0; mt < 4; ++mt) {
                short8 va = *(const short8*)(Vt + offV[kh][mt]);
#pragma unroll
                for (int nq = 0; nq < 2; ++nq)
                    o[mt][nq] = __builtin_amdgcn_mfma_f32_16x16x32_bf16(va, pb[kh][nq], o[mt][nq], 0, 0, 0);
            }
    }

    // reduce row-sums across the 4 quads (same lm); store UNNORMALIZED partials
#pragma unroll
    for (int nq = 0; nq < 2; ++nq) {
        float s = lsum[nq];
        s += __shfl_xor(s, 16);
        s += __shfl_xor(s, 32);
        lsum[nq] = s;
    }
    short* Op = half ? Op1 : Op0;
    float* Lp = half ? Lp1 : Lp0;
    short* OgBase = Op + ((size_t)bh * L_ + qt * 256) * HD_;
#pragma unroll
    for (int nq = 0; nq < 2; ++nq) {
        const int qrow = w * 32 + nq * 16 + lm;
#pragma unroll
        for (int mt = 0; mt < 4; ++mt) {
            short4v pk;
            pk.x = f2bf(o[mt][nq][0]);
            pk.y = f2bf(o[mt][nq][1]);
            pk.z = f2bf(o[mt][nq][2]);
            pk.w = f2bf(o[mt][nq][3]);
            *(short4v*)(OgBase + (size_t)qrow * 64 + mt * 16 + q * 4) = pk;
        }
    }
    if (l < 16) {
        const size_t rbase = (size_t)bh * L_ + qt * 256 + w * 32 + l;
        Lp[rbase]      = lsum[0];
        Lp[rbase + 16] = lsum[1];
    }
}

// ---------------------------------------------------------------------------
// Proj GEMM v5 (R15): combine fused into A-staging (reads both split-KV
// partials + row-sums, normalizes while staging); B operand back to bf16
// weights from cvt_all (R5's fp32-W read cost extra L2/VALU). out = O Wp^T,
// fp32 out. 64x128, BK=32, reg-prefetch dist 2 + LDS dbuf + 1 barrier/iter,
// padded LDS rows (40). XCD swizzle (W L2-resident).
// ---------------------------------------------------------------------------
#define LDA_ 40   // proj padded LDS row stride (shorts), BK=32
__global__ __launch_bounds__(256) void gemm_proj_fused(const short* __restrict__ Op0,
                                                       const short* __restrict__ Op1,
                                                       const float* __restrict__ Lp0,
                                                       const float* __restrict__ Lp1,
                                                       const short* __restrict__ Wp,
                                                       float* __restrict__ out) {
    __shared__ short As[2 * 2560];   // 64 x LDA_ per buf
    __shared__ short Bs[2 * 5120];   // 128 x LDA_ per buf
    const int tid = threadIdx.x;
    const int w = tid >> 6, l = tid & 63;
    const int lm = l & 15, q = l >> 4;
    const int bid = blockIdx.x;           // 0..511
    const int m0 = (bid >> 3) * 64, n0 = (bid & 7) * 128;
    const int wm = w & 1, wn = w >> 1;
    const int b = m0 >> 11, l0 = m0 & 2047;

    const int srow = tid >> 2;            // 0..63
    const int sc8  = (tid & 3) * 8;       // 0,8,16,24 (elements)
    const int aoff = srow * LDA_ + sc8;
    const int boff0 = aoff;
    const int boff1 = aoff + 64 * LDA_;
    const int arow_g = l0 + srow;         // token row this thread stages (fixed)
    const short* Bg = Wp + (size_t)(n0 + srow) * 1024 + sc8;

    float4v acc[2][4];
#pragma unroll
    for (int mt = 0; mt < 2; ++mt)
#pragma unroll
        for (int nt = 0; nt < 4; ++nt) acc[mt][nt] = (float4v){0.f, 0.f, 0.f, 0.f};

    {   // stage tile 0 directly: hh=0, d=sc8
        const size_t li = (size_t)(b * H_) * L_ + arow_g;
        const size_t ai = li * HD_ + sc8;
        short8 x0 = *(const short8*)(Op0 + ai);
        short8 x1 = *(const short8*)(Op1 + ai);
        const float inv = 1.f / (Lp0[li] + Lp1[li]);
        short8 r;
#pragma unroll
        for (int j = 0; j < 8; ++j)
            r[j] = f2bf((bf2f(x0[j]) + bf2f(x1[j])) * inv);
        *(short8*)(As + aoff) = r;
        *(short8*)(Bs + boff0) = *(const short8*)(Bg);
        *(short8*)(Bs + boff1) = *(const short8*)(Bg + 64 * 1024);
    }
    // tile 1 -> regs: hh=0, d=32+sc8
    short8 ap0, ap1;
    float lsA;
    {
        const size_t li = (size_t)(b * H_) * L_ + arow_g;
        const size_t ai = li * HD_ + 32 + sc8;
        ap0 = *(const short8*)(Op0 + ai);
        ap1 = *(const short8*)(Op1 + ai);
        lsA = Lp0[li] + Lp1[li];
    }
    short8 brx0 = *(const short8*)(Bg + 32);
    short8 brx1 = *(const short8*)(Bg + 64 * 1024 + 32);

    for (int t = 0; t < 32; ++t) {
        const int cur = t & 1;
        short* Asc = As + cur * 2560;
        short* Asn = As + (1 - cur) * 2560;
        short* Bsc = Bs + cur * 5120;
        short* Bsn = Bs + (1 - cur) * 5120;

        __syncthreads();

        if (t < 31) {
            const float inv = 1.f / lsA;
            short8 r;
#pragma unroll
            for (int j = 0; j < 8; ++j)
                r[j] = f2bf((bf2f(ap0[j]) + bf2f(ap1[j])) * inv);
            *(short8*)(Asn + aoff) = r;
            *(short8*)(Bsn + boff0) = brx0;
            *(short8*)(Bsn + boff1) = brx1;
        }
        if (t < 30) {
            const int tn = t + 2;
            const int hh = tn >> 1, d = (tn & 1) * 32 + sc8;
            const size_t li = (size_t)(b * H_ + hh) * L_ + arow_g;
            const size_t ai = li * HD_ + d;
            ap0 = *(const short8*)(Op0 + ai);
            ap1 = *(const short8*)(Op1 + ai);
            lsA = Lp0[li] + Lp1[li];
            brx0 = *(const short8*)(Bg + tn * 32);
            brx1 = *(const short8*)(Bg + 64 * 1024 + tn * 32);
        }

        short8 af[2], bfr[4];
#pragma unroll
        for (int mt = 0; mt < 2; ++mt)
            af[mt] = *(const short8*)(Asc + (wm * 32 + mt * 16 + lm) * LDA_ + q * 8);
#pragma unroll
        for (int nt = 0; nt < 4; ++nt)
            bfr[nt] = *(const short8*)(Bsc + (wn * 64 + nt * 16 + lm) * LDA_ + q * 8);
#pragma unroll
        for (int mt = 0; mt < 2; ++mt)
#pragma unroll
            for (int nt = 0; nt < 4; ++nt)
                acc[mt][nt] = __builtin_amdgcn_mfma_f32_16x16x32_bf16(af[mt], bfr[nt], acc[mt][nt], 0, 0, 0);
    }

#pragma unroll
    for (int mt = 0; mt < 2; ++mt)
#pragma unroll
        for (int nt = 0; nt < 4; ++nt)
#pragma unroll
            for (int r = 0; r < 4; ++r) {
                const int m = m0 + wm * 32 + mt * 16 + q * 4 + r;
                const int n = n0 + wn * 64 + nt * 16 + lm;
                out[(size_t)m * 1024 + n] = acc[mt][nt][r];
            }
}

// ---------------------------------------------------------------------------
extern "C" void kernel_launch(void* const* d_in, const int* in_sizes, int n_in,
                              void* d_out, int out_size, void* d_ws, size_t ws_size,
                              hipStream_t stream) {
    (void)in_sizes; (void)n_in; (void)out_size; (void)ws_size;
    const float* x      = (const float*)d_in[0];
    const float* w_qkv  = (const float*)d_in[1];
    const float* w_proj = (const float*)d_in[2];

    char* ws = (char*)d_ws;                       // 48 MiB used, dead-region reuse:
    short* xb     = (short*)(ws);                 // 8 MiB  (dead after qkv -> Op0)
    short* wqkvb  = (short*)(ws + (8u  << 20));   // 6 MiB  (dead after qkv -> Lp0/Lp1)
    short* wprojb = (short*)(ws + (14u << 20));   // 2 MiB  (live until proj)
    short* Qb     = (short*)(ws + (16u << 20));   // 8 MiB  [b,h,l,d], scaled
    short* Kb     = (short*)(ws + (24u << 20));   // 8 MiB  [b,h,l,d]
    short* Vb     = (short*)(ws + (32u << 20));   // 8 MiB  [b,h,d,slot] pi-permuted V^T
    short* Op1    = (short*)(ws + (40u << 20));   // 8 MiB  partial O, kv-half 1

    short* Op0 = xb;                              // partial O, kv-half 0
    float* Lp0 = (float*)(ws + (8u << 20));             // 256 KB row-sums half 0
    float* Lp1 = (float*)(ws + (8u << 20) + (256u << 10)); // 256 KB row-sums half 1

    cvt_all        <<<8192, 256, 0, stream>>>(x, w_qkv, w_proj, xb, wqkvb, wprojb);
    gemm_qkv_bf16  <<<768, 512, 0, stream>>>(xb, wqkvb, Qb, Kb, Vb);
    attn_mfma      <<<512, 512, 0, stream>>>(Qb, Kb, Vb, Op0, Op1, Lp0, Lp1);
    gemm_proj_fused<<<512, 256, 0, stream>>>(Op0, Op1, Lp0, Lp1, wprojb, (float*)d_out);
}